// Round 1
// baseline (29596.768 us; speedup 1.0000x reference)
//
#include <hip/hip_runtime.h>
#include <stdint.h>

// LSTM (linear cell/output activation) h_last, S=8192, D_IN=1024, H=2048.
// Persistent kernel: 256 WGs x 256 threads, 1 WG/CU. Each WG owns 8 h-indices
// (32 columns of U/W across the 4 gates). U slice in VGPRs (f16x2), W slice in
// LDS (f16x2). Per step: fused x@W + h@U, gates, then device-wide h exchange
// through LLC using relaxed agent-scope u64 atomics {tag, value}.

#define S_LEN   8192
#define D_INP   1024
#define HDIM    2048
#define FH      8192      // 4*HDIM
#define NWG     256
#define TPB     256
#define XB      8         // x rows staged per LDS block
#define KP_U    128       // k-pairs per thread for U (256 k values)
#define KP_W    64        // k-pairs per thread for W (128 k values)

typedef _Float16 half2_t __attribute__((ext_vector_type(2)));

#if defined(__has_builtin)
#if __has_builtin(__builtin_amdgcn_fdot2)
#define HAVE_FDOT2 1
#endif
#endif

__device__ __forceinline__ float fdot2f(uint32_t a, uint32_t b, float c) {
#ifdef HAVE_FDOT2
    return __builtin_amdgcn_fdot2(__builtin_bit_cast(half2_t, a),
                                  __builtin_bit_cast(half2_t, b), c, false);
#else
    half2_t ha = __builtin_bit_cast(half2_t, a);
    half2_t hb = __builtin_bit_cast(half2_t, b);
    c = fmaf((float)ha.x, (float)hb.x, c);
    c = fmaf((float)ha.y, (float)hb.y, c);
    return c;
#endif
}

__device__ __forceinline__ uint32_t pack2(float a, float b) {
    half2_t h;
    h.x = (_Float16)a;
    h.y = (_Float16)b;
    return __builtin_bit_cast(uint32_t, h);
}

__device__ __forceinline__ float sigmoidf_fast(float z) {
    return 1.0f / (1.0f + __expf(-z));
}

extern "C" __global__ void __launch_bounds__(TPB, 1)
lstm_persist(const float* __restrict__ x, const float* __restrict__ W,
             const float* __restrict__ U, const float* __restrict__ b,
             float* __restrict__ out, unsigned long long* __restrict__ hbuf)
{
    // LDS: W slice [512 kpairs][32 cols] f16x2 = 64 KB, x block [8][512] = 16 KB,
    // h packed [1024] = 4 KB, partials [8][32] = 1 KB.  Total ~85 KB -> 1 WG/CU.
    __shared__ __align__(16) uint32_t Wl[512 * 32];
    __shared__ __align__(16) uint32_t xl[XB * 512];
    __shared__ __align__(16) uint32_t hl[1024];
    __shared__ float zpart[8 * 32];

    const int tid = threadIdx.x;
    const int wg  = blockIdx.x;
    const int c   = tid & 31;   // local column 0..31  (gate = c>>3, idx = c&7)
    const int kc  = tid >> 5;   // k-chunk 0..7 (256 k values each)
    const int g   = c >> 3;
    const int j   = c & 7;
    const int gc  = g * HDIM + wg * 8 + j;   // global column in [0, 4H)

    // ---- one-time init: U slice -> registers, W slice -> LDS ----
    uint32_t ureg[KP_U];
#pragma unroll
    for (int i = 0; i < KP_U; ++i) {
        const int k0 = kc * 256 + 2 * i;
        const float u0 = U[(size_t)k0 * FH + gc];
        const float u1 = U[(size_t)(k0 + 1) * FH + gc];
        ureg[i] = pack2(u0, u1);
    }
#pragma unroll 4
    for (int i = 0; i < KP_W; ++i) {
        const int kp = kc * KP_W + i;
        const float w0 = W[(size_t)(2 * kp) * FH + gc];
        const float w1 = W[(size_t)(2 * kp + 1) * FH + gc];
        Wl[kp * 32 + c] = pack2(w0, w1);
    }
    const float bias = (tid < 32) ? b[gc] : 0.0f;
    float c_state = 0.0f;
    __syncthreads();

    unsigned long long* const hb0 = hbuf;          // slot 0
    unsigned long long* const hb1 = hbuf + 2048;   // slot 1

    for (int t = 0; t < S_LEN; ++t) {
        const int s = t & (XB - 1);
        if (s == 0) {
            // stage x rows [t, t+XB) into LDS as packed f16x2
#pragma unroll
            for (int i = 0; i < 16; ++i) {
                const int idx = tid * 16 + i;       // 0..4095
                const int row = idx >> 9;           // 0..7
                const int kp  = idx & 511;          // 0..511
                const float2 v = *reinterpret_cast<const float2*>(
                    &x[(size_t)(t + row) * D_INP + 2 * kp]);
                xl[row * 512 + kp] = pack2(v.x, v.y);
            }
            __syncthreads();
        }

        // ---- input projection part: acc = sum_k x_t[k] * W[k, gc] ----
        float acc = 0.0f;
#pragma unroll
        for (int i = 0; i < KP_W; ++i) {
            const int kp = kc * KP_W + i;
            acc = fdot2f(Wl[kp * 32 + c], xl[s * 512 + kp], acc);
        }

        // ---- gather h_t from all 256 producers (thread i <-> producer i) ----
        if (t > 0) {
            unsigned long long* const src = ((t & 1) ? hb1 : hb0) + tid * 8;
            float hv[8];
            unsigned int got = 0;
            int guard = 0;
            while (got != 0xFFu && guard < (1 << 20)) {
                ++guard;
#pragma unroll
                for (int q = 0; q < 8; ++q) {
                    if (!(got & (1u << q))) {
                        const unsigned long long v = __hip_atomic_load(
                            &src[q], __ATOMIC_RELAXED, __HIP_MEMORY_SCOPE_AGENT);
                        if ((unsigned int)(v >> 32) == (unsigned int)t) {
                            hv[q] = __builtin_bit_cast(float, (unsigned int)v);
                            got |= (1u << q);
                        }
                    }
                }
                if (got != 0xFFu) __builtin_amdgcn_s_sleep(1);
            }
            uint4 q4;
            q4.x = pack2(hv[0], hv[1]);
            q4.y = pack2(hv[2], hv[3]);
            q4.z = pack2(hv[4], hv[5]);
            q4.w = pack2(hv[6], hv[7]);
            *reinterpret_cast<uint4*>(&hl[tid * 4]) = q4;
        } else {
            const uint4 z4 = {0u, 0u, 0u, 0u};
            *reinterpret_cast<uint4*>(&hl[tid * 4]) = z4;   // h_0 = 0
        }
        __syncthreads();

        // ---- recurrent part: acc += sum_k h_t[k] * U[k, gc] ----
#pragma unroll
        for (int i = 0; i < KP_U; ++i) {
            acc = fdot2f(ureg[i], hl[kc * KP_U + i], acc);
        }
        zpart[kc * 32 + c] = acc;
        __syncthreads();

        // ---- reduce across k-chunks, gates, publish (wave 0, lanes < 32) ----
        if (tid < 32) {
            float z = bias;
#pragma unroll
            for (int r = 0; r < 8; ++r) z += zpart[r * 32 + c];
            // lane c holds z for local col c; pull the other 3 gates via shfl
            const float z_f = __shfl(z, (c & 7) + 8);
            const float z_g = __shfl(z, (c & 7) + 16);
            const float z_o = __shfl(z, (c & 7) + 24);
            if (c < 8) {
                const float si = sigmoidf_fast(z);     // gate i (own col)
                const float sf = sigmoidf_fast(z_f);   // gate f
                const float so = sigmoidf_fast(z_o);   // gate o
                const float cn = sf * c_state + si * z_g;  // linear candidate
                c_state = cn;
                const float hn = so * cn;                  // linear output act
                if (t < S_LEN - 1) {
                    const unsigned long long pv =
                        ((unsigned long long)(unsigned int)(t + 1) << 32) |
                        (unsigned long long)__builtin_bit_cast(unsigned int, hn);
                    unsigned long long* const dst =
                        (((t + 1) & 1) ? hb1 : hb0) + wg * 8 + c;
                    __hip_atomic_store(dst, pv, __ATOMIC_RELAXED,
                                       __HIP_MEMORY_SCOPE_AGENT);
                } else {
                    out[wg * 8 + c] = hn;   // final h -> d_out
                }
            }
        }
    }
}

extern "C" void kernel_launch(void* const* d_in, const int* in_sizes, int n_in,
                              void* d_out, int out_size, void* d_ws, size_t ws_size,
                              hipStream_t stream) {
    const float* x = (const float*)d_in[0];
    const float* W = (const float*)d_in[1];
    const float* U = (const float*)d_in[2];
    const float* b = (const float*)d_in[3];
    unsigned long long* hbuf = (unsigned long long*)d_ws;

    // Reset exchange tags every launch (replays must re-synchronize for real).
    hipMemsetAsync(hbuf, 0, (size_t)2 * 2048 * sizeof(unsigned long long), stream);

    hipLaunchKernelGGL(lstm_persist, dim3(NWG), dim3(TPB), 0, stream,
                       x, W, U, b, (float*)d_out, hbuf);
}